// Round 1
// 581.177 us; speedup vs baseline: 1.1364x; 1.1364x over previous
//
#include <hip/hip_runtime.h>
#include <stdint.h>

// Qwen3 MoE sparse block: T=4096 tokens, D=2048, E=16, F=768, top-2.
// R3: 2-phase double-buffered K-loops (T3-minimum), atomic-free expertB
//     (slot-major O + combine kernel, O aliases gbf/ubf), x-cvt fused into
//     router, weight-cvt merged into one launch, Hs aliased over staging.

#define NTOK 4096
#define DIM  2048
#define NEXP 16
#define FDIM 768
#define BK   32

// shared control layout (int offsets into d_ws)
#define WS_CNT     0       // cnt[e] at e*16
#define WS_CUR     256
#define WS_NTILES  512
#define WS_TILE_E  576     // up to 144
#define WS_TILE_B  736
#define WS_TOKE    1024    // int[8192]
#define WS_TOKW    9216    // float[8192]
#define WS_SLOTT   17408   // int[<=10240]
#define SLOTW_NEW  27648   // float[10240]
#define SLOTW_OLD  26624   // float[9216]  (R1 layout, proven to fit)
#define WS_TOKSLOT 40960   // int[8192]: token -> slot (for combine)
#define MAX_TILES  144

// new-path geometry
#define TMN 128
#define TNA 64            // expertA N tile
#define TNB 128           // expertB N tile
#define MAX_SLOTS_N 10240
#define MAX_TILES_N 80
// fallback geometry (R1)
#define TMO 64
#define MAX_SLOTS_O 9216

// new-path byte layout in ws
#define B_XBF  262144ull
#define B_H    (B_XBF + (size_t)NTOK*DIM*2)            // 17,039,360
#define B_GBF  (B_H + (size_t)MAX_SLOTS_N*FDIM*2)      // 32,768,000
#define B_UBF  (B_GBF + (size_t)NEXP*FDIM*DIM*2)
#define B_DBF  (B_UBF + (size_t)NEXP*FDIM*DIM*2)
#define WS_NEED (B_DBF + (size_t)NEXP*FDIM*DIM*2)      // ~183.8 MB
// O_slots fp32 [MAX_SLOTS_N][DIM] = 83.9MB aliases gbf+ubf (100.6MB):
// expertA (reads gbf/ubf) completes before expertB writes O (same stream);
// next iteration's cvtw_k rewrites gbf/ubf before expertA reads again.
#define B_OSL  B_GBF
#define B_HOLD 143360ull                               // fallback H (R1, proven)

typedef __attribute__((ext_vector_type(8))) short short8;
typedef __attribute__((ext_vector_type(4))) float f32x4;

__device__ __forceinline__ unsigned short f2bf(float f) {
    unsigned u = __float_as_uint(f);
    return (unsigned short)((u + 0x7FFFu + ((u >> 16) & 1u)) >> 16);  // RNE
}

__device__ __forceinline__ short8 cvt8(float4 v0, float4 v1) {
    short8 s;
    s[0] = (short)f2bf(v0.x); s[1] = (short)f2bf(v0.y);
    s[2] = (short)f2bf(v0.z); s[3] = (short)f2bf(v0.w);
    s[4] = (short)f2bf(v1.x); s[5] = (short)f2bf(v1.y);
    s[6] = (short)f2bf(v1.z); s[7] = (short)f2bf(v1.w);
    return s;
}

__device__ __forceinline__ void gl_lds16(const void* g, void* l) {
    __builtin_amdgcn_global_load_lds(
        (const __attribute__((address_space(1))) unsigned int*)g,
        (__attribute__((address_space(3))) unsigned int*)l, 16, 0, 0);
}

// ---------------- fp32 -> bf16 weight convert (3 tensors, one launch) ----------------
__global__ __launch_bounds__(256) void cvtw_k(
    const float* __restrict__ g, const float* __restrict__ u, const float* __restrict__ d,
    unsigned short* __restrict__ go, unsigned short* __restrict__ uo,
    unsigned short* __restrict__ dd, int n8)
{
    int i = blockIdx.x * 256 + threadIdx.x;
    if (i >= n8) return;
    const float* s;
    unsigned short* o;
    if (blockIdx.y == 0)      { s = g; o = go; }
    else if (blockIdx.y == 1) { s = u; o = uo; }
    else                      { s = d; o = dd; }
    const float4* p = (const float4*)(s + (size_t)i * 8);
    *(short8*)(o + (size_t)i * 8) = cvt8(p[0], p[1]);
}

// ---------------- router: logits (fp32) + top2 + histogram + x->bf16 ----------------
__global__ __launch_bounds__(256) void router_k(
    const float* __restrict__ x, const float* __restrict__ rw,
    float* __restrict__ logits_out, int* __restrict__ wsi, float* __restrict__ wsf,
    unsigned short* __restrict__ xbf)
{
    int wid = threadIdx.x >> 6, lane = threadIdx.x & 63;
    int t = blockIdx.x * 4 + wid;
    const float* xr = x + (size_t)t * DIM;

    float acc[NEXP];
#pragma unroll
    for (int e = 0; e < NEXP; e++) acc[e] = 0.f;
    for (int i = 0; i < DIM / 64; i++) {
        float xv = xr[i * 64 + lane];
        if (xbf) xbf[(size_t)t * DIM + i * 64 + lane] = f2bf(xv);
#pragma unroll
        for (int e = 0; e < NEXP; e++) acc[e] += xv * rw[e * DIM + i * 64 + lane];
    }
#pragma unroll
    for (int e = 0; e < NEXP; e++) {
        float v = acc[e];
        for (int off = 32; off; off >>= 1) v += __shfl_down(v, off);
        acc[e] = v;
    }
    if (lane == 0) {
#pragma unroll
        for (int e = 0; e < NEXP; e++) logits_out[t * NEXP + e] = acc[e];
        int i0 = 0; float m0 = acc[0];
#pragma unroll
        for (int e = 1; e < NEXP; e++) if (acc[e] > m0) { m0 = acc[e]; i0 = e; }
        int i1 = -1; float m1 = -3.4e38f;
#pragma unroll
        for (int e = 0; e < NEXP; e++) if (e != i0 && acc[e] > m1) { m1 = acc[e]; i1 = e; }
        float w0 = 1.f / (1.f + __expf(m1 - m0));
        wsi[WS_TOKE + t * 2 + 0] = i0;
        wsi[WS_TOKE + t * 2 + 1] = i1;
        wsf[WS_TOKW + t * 2 + 0] = w0;
        wsf[WS_TOKW + t * 2 + 1] = 1.f - w0;
        atomicAdd(&wsi[WS_CNT + i0 * 16], 1);
        atomicAdd(&wsi[WS_CNT + i1 * 16], 1);
    }
}

// ---------------- scan: padded offsets + tile map + slot init ----------------
__global__ void scan_k(int* __restrict__ wsi, float* __restrict__ wsf,
                       int tm, int slotw, int max_slots)
{
    if (threadIdx.x == 0) {
        int total = 0, tiles = 0;
        for (int e = 0; e < NEXP; e++) {
            int c = wsi[WS_CNT + e * 16];
            int nt = (c + tm - 1) / tm;
            wsi[WS_CNT + e * 16] = total;
            for (int j = 0; j < nt; j++) {
                wsi[WS_TILE_E + tiles] = e;
                wsi[WS_TILE_B + tiles] = total + j * tm;
                tiles++;
            }
            total += nt * tm;
        }
        wsi[WS_NTILES] = tiles;
    }
    for (int s = threadIdx.x; s < max_slots; s += blockDim.x) {
        wsi[WS_SLOTT + s] = 0;
        wsf[slotw + s] = 0.f;
    }
}

// ---------------- scatter: token -> slot (+ token->slot map) ----------------
__global__ __launch_bounds__(256) void scatter_k(int* __restrict__ wsi,
                                                 float* __restrict__ wsf, int slotw)
{
    int t = blockIdx.x * blockDim.x + threadIdx.x;
    if (t >= NTOK) return;
#pragma unroll
    for (int k = 0; k < 2; k++) {
        int e = wsi[WS_TOKE + t * 2 + k];
        float w = wsf[WS_TOKW + t * 2 + k];
        int pos = atomicAdd(&wsi[WS_CUR + e * 16], 1);
        int s = wsi[WS_CNT + e * 16] + pos;
        wsi[WS_SLOTT + s] = t;
        wsf[slotw + s] = w;
        wsi[WS_TOKSLOT + t * 2 + k] = s;
    }
}

// ================= NEW PATH (bf16, gl_lds, 2-phase double-buffered) =================

// expertA: H = silu(X gate^T) * (X up^T) * w   [128 x 64 tile]
__global__ __launch_bounds__(256) void expertA_k(
    const unsigned short* __restrict__ xbf,
    const unsigned short* __restrict__ gbf,
    const unsigned short* __restrict__ ubf,
    const int* __restrict__ wsi, const float* __restrict__ wsf,
    unsigned short* __restrict__ H)
{
    __shared__ union {
        struct {
            unsigned short A[2][TMN * BK];   // 16 KB (dbuf)
            unsigned short G[2][TNA * BK];   //  8 KB
            unsigned short U[2][TNA * BK];   //  8 KB
        } st;
        unsigned short Hs[TMN][TNA + 8];     // 18.4 KB (epilogue only, aliased)
    } sh;
    __shared__ int   Ts[TMN];
    __shared__ float Wl[TMN];

    int tile = blockIdx.y;
    if (tile >= wsi[WS_NTILES]) return;
    int e     = wsi[WS_TILE_E + tile];
    int slot0 = wsi[WS_TILE_B + tile];
    int f0    = blockIdx.x * TNA;
    int tid   = threadIdx.x;

    if (tid < TMN) {
        Ts[tid] = wsi[WS_SLOTT + slot0 + tid];
        Wl[tid] = wsf[SLOTW_NEW + slot0 + tid];
    }
    __syncthreads();

    int r0 = tid >> 2, seg = tid & 3;
    const unsigned short* ap0 = xbf + (size_t)Ts[r0] * DIM + seg * 8;
    const unsigned short* ap1 = xbf + (size_t)Ts[64 + r0] * DIM + seg * 8;
    const unsigned short* gp  = gbf + ((size_t)e * FDIM + f0 + r0) * DIM + seg * 8;
    const unsigned short* up  = ubf + ((size_t)e * FDIM + f0 + r0) * DIM + seg * 8;

    int wid = tid >> 6, lane = tid & 63;
    int wm = (wid >> 1) * 64, wn = (wid & 1) * 32;
    int lr = lane & 15, lk = (lane >> 4) * 8;

    f32x4 accg[4][2], accu[4][2];
#pragma unroll
    for (int i = 0; i < 4; i++)
#pragma unroll
        for (int j = 0; j < 2; j++) { accg[i][j] = (f32x4)0.f; accu[i][j] = (f32x4)0.f; }

    auto stage = [&](int b, int k0) {
        gl_lds16(ap0 + k0, &sh.st.A[b][(size_t)tid * 8]);
        gl_lds16(ap1 + k0, &sh.st.A[b][(size_t)(256 + tid) * 8]);
        gl_lds16(gp + k0,  &sh.st.G[b][(size_t)tid * 8]);
        gl_lds16(up + k0,  &sh.st.U[b][(size_t)tid * 8]);
    };
    auto comp = [&](int b) {
        short8 a[4], g[2], u[2];
#pragma unroll
        for (int mi = 0; mi < 4; mi++)
            a[mi] = *(const short8*)&sh.st.A[b][(wm + mi * 16 + lr) * BK + lk];
#pragma unroll
        for (int nj = 0; nj < 2; nj++) {
            g[nj] = *(const short8*)&sh.st.G[b][(wn + nj * 16 + lr) * BK + lk];
            u[nj] = *(const short8*)&sh.st.U[b][(wn + nj * 16 + lr) * BK + lk];
        }
#pragma unroll
        for (int mi = 0; mi < 4; mi++)
#pragma unroll
            for (int nj = 0; nj < 2; nj++) {
                accg[mi][nj] = __builtin_amdgcn_mfma_f32_16x16x32_bf16(a[mi], g[nj], accg[mi][nj], 0, 0, 0);
                accu[mi][nj] = __builtin_amdgcn_mfma_f32_16x16x32_bf16(a[mi], u[nj], accu[mi][nj], 0, 0, 0);
            }
    };

    // 2-phase: prefetch next K-tile before computing current; one barrier per step.
    stage(0, 0);
    __syncthreads();
    for (int k0 = 0; k0 < DIM; k0 += 2 * BK) {
        if (k0 + BK < DIM) stage(1, k0 + BK);
        comp(0);
        __syncthreads();
        if (k0 + 2 * BK < DIM) stage(0, k0 + 2 * BK);
        comp(1);
        __syncthreads();
    }

    // epilogue: h = silu(g)*u*w -> Hs (bf16); Hs aliases staging (safe after barrier)
#pragma unroll
    for (int mi = 0; mi < 4; mi++)
#pragma unroll
        for (int nj = 0; nj < 2; nj++)
#pragma unroll
            for (int r = 0; r < 4; r++) {
                int m = wm + mi * 16 + (lane >> 4) * 4 + r;
                int n = wn + nj * 16 + lr;
                float g = accg[mi][nj][r];
                float u = accu[mi][nj][r];
                float sg = g / (1.f + __expf(-g));
                sh.Hs[m][n] = f2bf(sg * u * Wl[m]);
            }
    __syncthreads();

    // coalesced store: 128 rows x 64 bf16; 2 threads/row x 32 elems
    int row = tid >> 1, cb = (tid & 1) * 32;
    unsigned short* dst = H + (size_t)(slot0 + row) * FDIM + f0 + cb;
#pragma unroll
    for (int c = 0; c < 4; c++)
        *(short8*)(dst + c * 8) = *(const short8*)&sh.Hs[row][cb + c * 8];
}

// expertB: O[slot] = H @ down^T  [128 x 128 tile, plain slot-major stores]
__global__ __launch_bounds__(256) void expertB_k(
    const unsigned short* __restrict__ H, const unsigned short* __restrict__ dbf,
    const int* __restrict__ wsi, float* __restrict__ O)
{
    __shared__ unsigned short As[2][TMN * BK];   // 16 KB
    __shared__ unsigned short Bs[2][TNB * BK];   // 16 KB

    int tile = blockIdx.y;
    if (tile >= wsi[WS_NTILES]) return;
    int e     = wsi[WS_TILE_E + tile];
    int slot0 = wsi[WS_TILE_B + tile];
    int d0    = blockIdx.x * TNB;
    int tid   = threadIdx.x;

    int r0 = tid >> 2, seg = tid & 3;
    const unsigned short* ap0 = H + (size_t)(slot0 + r0) * FDIM + seg * 8;
    const unsigned short* ap1 = H + (size_t)(slot0 + 64 + r0) * FDIM + seg * 8;
    const unsigned short* bp0 = dbf + ((size_t)e * DIM + d0 + r0) * FDIM + seg * 8;
    const unsigned short* bp1 = dbf + ((size_t)e * DIM + d0 + 64 + r0) * FDIM + seg * 8;

    int wid = tid >> 6, lane = tid & 63;
    int wm = (wid >> 1) * 64, wn = (wid & 1) * 64;
    int lr = lane & 15, lk = (lane >> 4) * 8;

    f32x4 acc[4][4];
#pragma unroll
    for (int i = 0; i < 4; i++)
#pragma unroll
        for (int j = 0; j < 4; j++) acc[i][j] = (f32x4)0.f;

    auto stage = [&](int b, int k0) {
        gl_lds16(ap0 + k0, &As[b][(size_t)tid * 8]);
        gl_lds16(ap1 + k0, &As[b][(size_t)(256 + tid) * 8]);
        gl_lds16(bp0 + k0, &Bs[b][(size_t)tid * 8]);
        gl_lds16(bp1 + k0, &Bs[b][(size_t)(256 + tid) * 8]);
    };
    auto comp = [&](int bb) {
        short8 a[4], b[4];
#pragma unroll
        for (int i = 0; i < 4; i++) {
            a[i] = *(const short8*)&As[bb][(wm + i * 16 + lr) * BK + lk];
            b[i] = *(const short8*)&Bs[bb][(wn + i * 16 + lr) * BK + lk];
        }
#pragma unroll
        for (int mi = 0; mi < 4; mi++)
#pragma unroll
            for (int nj = 0; nj < 4; nj++)
                acc[mi][nj] = __builtin_amdgcn_mfma_f32_16x16x32_bf16(a[mi], b[nj], acc[mi][nj], 0, 0, 0);
    };

    stage(0, 0);
    __syncthreads();
    for (int k0 = 0; k0 < FDIM; k0 += 2 * BK) {
        if (k0 + BK < FDIM) stage(1, k0 + BK);
        comp(0);
        __syncthreads();
        if (k0 + 2 * BK < FDIM) stage(0, k0 + 2 * BK);
        comp(1);
        __syncthreads();
    }

    // slot-major store (no atomics); padded slots written but never read
#pragma unroll
    for (int mi = 0; mi < 4; mi++)
#pragma unroll
        for (int nj = 0; nj < 4; nj++)
#pragma unroll
            for (int r = 0; r < 4; r++) {
                int m = wm + mi * 16 + (lane >> 4) * 4 + r;
                int n = d0 + wn + nj * 16 + lr;
                O[(size_t)(slot0 + m) * DIM + n] = acc[mi][nj][r];
            }
}

// combine: out[t] = O[slot0(t)] + O[slot1(t)]  (streaming, float4)
__global__ __launch_bounds__(256) void combine_k(
    const float* __restrict__ O, const int* __restrict__ wsi, float* __restrict__ out)
{
    int i = blockIdx.x * 256 + threadIdx.x;      // over NTOK*DIM/4 float4s
    int t = i >> 9, c = i & 511;                 // DIM/4 = 512
    int s0 = wsi[WS_TOKSLOT + t * 2 + 0];
    int s1 = wsi[WS_TOKSLOT + t * 2 + 1];
    float4 a = *((const float4*)(O + (size_t)s0 * DIM) + c);
    float4 b = *((const float4*)(O + (size_t)s1 * DIM) + c);
    float4 r;
    r.x = a.x + b.x; r.y = a.y + b.y; r.z = a.z + b.z; r.w = a.w + b.w;
    *((float4*)(out + (size_t)t * DIM) + c) = r;
}

// ================= FALLBACK PATH (R1 proven kernels, ~14.4 MB ws) =================

__global__ __launch_bounds__(256) void expertA64_k(
    const float* __restrict__ x, const float* __restrict__ gw, const float* __restrict__ uw,
    const int* __restrict__ wsi, const float* __restrict__ wsf,
    unsigned short* __restrict__ H)
{
    __shared__ unsigned short As[TMO][40];
    __shared__ unsigned short Bg[TMO][40];
    __shared__ unsigned short Bu[TMO][40];
    __shared__ unsigned short Hs[TMO][72];
    __shared__ int   Ts[TMO];
    __shared__ float Wl[TMO];

    int tile = blockIdx.y;
    if (tile >= wsi[WS_NTILES]) return;
    int e     = wsi[WS_TILE_E + tile];
    int slot0 = wsi[WS_TILE_B + tile];
    int f0    = blockIdx.x * 64;
    int tid   = threadIdx.x;

    if (tid < TMO) {
        Ts[tid] = wsi[WS_SLOTT + slot0 + tid];
        Wl[tid] = wsf[SLOTW_OLD + slot0 + tid];
    }
    __syncthreads();

    int row = tid >> 2, seg = tid & 3;
    const float* aRow = x  + (size_t)Ts[row] * DIM + seg * 8;
    const float* gRow = gw + ((size_t)e * FDIM + f0 + row) * DIM + seg * 8;
    const float* uRow = uw + ((size_t)e * FDIM + f0 + row) * DIM + seg * 8;

    int wid = tid >> 6, lane = tid & 63;
    int wm = (wid >> 1) * 32, wn = (wid & 1) * 32;
    int lr = lane & 15, lk = (lane >> 4) * 8;

    f32x4 accg[2][2], accu[2][2];
#pragma unroll
    for (int i = 0; i < 2; i++)
#pragma unroll
        for (int j = 0; j < 2; j++) { accg[i][j] = (f32x4)0.f; accu[i][j] = (f32x4)0.f; }

    for (int k0 = 0; k0 < DIM; k0 += BK) {
        { const float4* p = (const float4*)(aRow + k0); *(short8*)&As[row][seg * 8] = cvt8(p[0], p[1]); }
        { const float4* p = (const float4*)(gRow + k0); *(short8*)&Bg[row][seg * 8] = cvt8(p[0], p[1]); }
        { const float4* p = (const float4*)(uRow + k0); *(short8*)&Bu[row][seg * 8] = cvt8(p[0], p[1]); }
        __syncthreads();
        short8 a0 = *(const short8*)&As[wm + lr][lk];
        short8 a1 = *(const short8*)&As[wm + 16 + lr][lk];
        short8 g0 = *(const short8*)&Bg[wn + lr][lk];
        short8 g1 = *(const short8*)&Bg[wn + 16 + lr][lk];
        short8 u0 = *(const short8*)&Bu[wn + lr][lk];
        short8 u1 = *(const short8*)&Bu[wn + 16 + lr][lk];
        accg[0][0] = __builtin_amdgcn_mfma_f32_16x16x32_bf16(a0, g0, accg[0][0], 0, 0, 0);
        accg[0][1] = __builtin_amdgcn_mfma_f32_16x16x32_bf16(a0, g1, accg[0][1], 0, 0, 0);
        accg[1][0] = __builtin_amdgcn_mfma_f32_16x16x32_bf16(a1, g0, accg[1][0], 0, 0, 0);
        accg[1][1] = __builtin_amdgcn_mfma_f32_16x16x32_bf16(a1, g1, accg[1][1], 0, 0, 0);
        accu[0][0] = __builtin_amdgcn_mfma_f32_16x16x32_bf16(a0, u0, accu[0][0], 0, 0, 0);
        accu[0][1] = __builtin_amdgcn_mfma_f32_16x16x32_bf16(a0, u1, accu[0][1], 0, 0, 0);
        accu[1][0] = __builtin_amdgcn_mfma_f32_16x16x32_bf16(a1, u0, accu[1][0], 0, 0, 0);
        accu[1][1] = __builtin_amdgcn_mfma_f32_16x16x32_bf16(a1, u1, accu[1][1], 0, 0, 0);
        __syncthreads();
    }
#pragma unroll
    for (int mi = 0; mi < 2; mi++)
#pragma unroll
        for (int ni = 0; ni < 2; ni++)
#pragma unroll
            for (int r = 0; r < 4; r++) {
                int m = wm + mi * 16 + (lane >> 4) * 4 + r;
                int n = wn + ni * 16 + lr;
                float g = accg[mi][ni][r];
                float u = accu[mi][ni][r];
                Hs[m][n] = f2bf((g / (1.f + __expf(-g))) * u * Wl[m]);
            }
    __syncthreads();
    unsigned short* dst = H + (size_t)(slot0 + row) * FDIM + f0 + seg * 16;
    *(short8*)dst       = *(const short8*)&Hs[row][seg * 16];
    *(short8*)(dst + 8) = *(const short8*)&Hs[row][seg * 16 + 8];
}

__global__ __launch_bounds__(256) void expertB64_k(
    const unsigned short* __restrict__ H, const float* __restrict__ dw,
    const int* __restrict__ wsi, float* __restrict__ out)
{
    __shared__ unsigned short As[TMO][40];
    __shared__ unsigned short Bd[TMO][40];
    __shared__ int Ts[TMO];

    int tile = blockIdx.y;
    if (tile >= wsi[WS_NTILES]) return;
    int e     = wsi[WS_TILE_E + tile];
    int slot0 = wsi[WS_TILE_B + tile];
    int d0    = blockIdx.x * 64;
    int tid   = threadIdx.x;

    if (tid < TMO) Ts[tid] = wsi[WS_SLOTT + slot0 + tid];
    __syncthreads();

    int row = tid >> 2, seg = tid & 3;
    const unsigned short* aRow = H + (size_t)(slot0 + row) * FDIM + seg * 8;
    const float* dRow = dw + ((size_t)e * DIM + d0 + row) * FDIM + seg * 8;

    int wid = tid >> 6, lane = tid & 63;
    int wm = (wid >> 1) * 32, wn = (wid & 1) * 32;
    int lr = lane & 15, lk = (lane >> 4) * 8;

    f32x4 acc[2][2];
#pragma unroll
    for (int i = 0; i < 2; i++)
#pragma unroll
        for (int j = 0; j < 2; j++) acc[i][j] = (f32x4)0.f;

    for (int k0 = 0; k0 < FDIM; k0 += BK) {
        *(short8*)&As[row][seg * 8] = *(const short8*)(aRow + k0);
        { const float4* p = (const float4*)(dRow + k0); *(short8*)&Bd[row][seg * 8] = cvt8(p[0], p[1]); }
        __syncthreads();
        short8 a0 = *(const short8*)&As[wm + lr][lk];
        short8 a1 = *(const short8*)&As[wm + 16 + lr][lk];
        short8 b0 = *(const short8*)&Bd[wn + lr][lk];
        short8 b1 = *(const short8*)&Bd[wn + 16 + lr][lk];
        acc[0][0] = __builtin_amdgcn_mfma_f32_16x16x32_bf16(a0, b0, acc[0][0], 0, 0, 0);
        acc[0][1] = __builtin_amdgcn_mfma_f32_16x16x32_bf16(a0, b1, acc[0][1], 0, 0, 0);
        acc[1][0] = __builtin_amdgcn_mfma_f32_16x16x32_bf16(a1, b0, acc[1][0], 0, 0, 0);
        acc[1][1] = __builtin_amdgcn_mfma_f32_16x16x32_bf16(a1, b1, acc[1][1], 0, 0, 0);
        __syncthreads();
    }
#pragma unroll
    for (int mi = 0; mi < 2; mi++)
#pragma unroll
        for (int ni = 0; ni < 2; ni++)
#pragma unroll
            for (int r = 0; r < 4; r++) {
                int m = wm + mi * 16 + (lane >> 4) * 4 + r;
                int n = d0 + wn + ni * 16 + lr;
                atomicAdd(&out[(size_t)Ts[m] * DIM + n], acc[mi][ni][r]);
            }
}

extern "C" void kernel_launch(void* const* d_in, const int* in_sizes, int n_in,
                              void* d_out, int out_size, void* d_ws, size_t ws_size,
                              hipStream_t stream) {
    const float* x  = (const float*)d_in[0];
    const float* rw = (const float*)d_in[1];
    const float* gw = (const float*)d_in[2];
    const float* uw = (const float*)d_in[3];
    const float* dw = (const float*)d_in[4];
    float* out    = (float*)d_out;
    float* logits = out + (size_t)NTOK * DIM;
    int*   wsi = (int*)d_ws;
    float* wsf = (float*)d_ws;

    hipMemsetAsync(d_ws, 0, 4096, stream);

    if (ws_size >= WS_NEED) {
        unsigned short* xbf = (unsigned short*)((char*)d_ws + B_XBF);
        unsigned short* H   = (unsigned short*)((char*)d_ws + B_H);
        unsigned short* gbf = (unsigned short*)((char*)d_ws + B_GBF);
        unsigned short* ubf = (unsigned short*)((char*)d_ws + B_UBF);
        unsigned short* dbf = (unsigned short*)((char*)d_ws + B_DBF);
        float*          Osl = (float*)((char*)d_ws + B_OSL);
        const int nw8 = NEXP * FDIM * DIM / 8;   // 3,145,728
        router_k<<<NTOK / 4, 256, 0, stream>>>(x, rw, logits, wsi, wsf, xbf);
        cvtw_k<<<dim3(nw8 / 256, 3), 256, 0, stream>>>(gw, uw, dw, gbf, ubf, dbf, nw8);
        scan_k   <<<1, 256, 0, stream>>>(wsi, wsf, TMN, SLOTW_NEW, MAX_SLOTS_N);
        scatter_k<<<NTOK / 256, 256, 0, stream>>>(wsi, wsf, SLOTW_NEW);
        expertA_k<<<dim3(FDIM / TNA, MAX_TILES_N), 256, 0, stream>>>(xbf, gbf, ubf, wsi, wsf, H);
        expertB_k<<<dim3(DIM / TNB, MAX_TILES_N), 256, 0, stream>>>(H, dbf, wsi, Osl);
        combine_k<<<NTOK * DIM / 4 / 256, 256, 0, stream>>>(Osl, wsi, out);
    } else {
        unsigned short* H = (unsigned short*)((char*)d_ws + B_HOLD);
        hipMemsetAsync(d_out, 0, (size_t)NTOK * DIM * sizeof(float), stream);
        router_k<<<NTOK / 4, 256, 0, stream>>>(x, rw, logits, wsi, wsf, nullptr);
        scan_k   <<<1, 256, 0, stream>>>(wsi, wsf, TMO, SLOTW_OLD, MAX_SLOTS_O);
        scatter_k<<<NTOK / 256, 256, 0, stream>>>(wsi, wsf, SLOTW_OLD);
        expertA64_k<<<dim3(FDIM / 64, MAX_TILES), 256, 0, stream>>>(x, gw, uw, wsi, wsf, H);
        expertB64_k<<<dim3(DIM / 64, MAX_TILES), 256, 0, stream>>>(H, dw, wsi, out);
    }
}